// Round 1
// 316.411 us; speedup vs baseline: 1.0115x; 1.0115x over previous
//
#include <hip/hip_runtime.h>
#include <math.h>

#define WIN 20
#define OFFSET 40
#define B_ 32
#define F_ 8192
#define C_ 256
#define P_ 256
#define SIL_SPLIT 16   // silence blocks per batch (each thread: exactly 2 predicated loads)

__global__ __launch_bounds__(256) void smoothed_loss_kernel(
    const float* __restrict__ X,
    const int* __restrict__ lengths,
    const int* __restrict__ tgt,
    const int* __restrict__ p_end,
    const int* __restrict__ phoneme_nums,
    float* __restrict__ out)
{
    __shared__ float sdata[4];
    const int tid = threadIdx.x;
    float contrib = 0.0f;

    if (blockIdx.x < B_) {
        // -------- phoneme windows: one thread per phoneme --------
        const int b = blockIdx.x;
        const int pn = phoneme_nums[b];
        const int len = lengths[b];
        const int end_ph = min(p_end[b] + OFFSET, len);
        const int p = tid;
        if (p < pn) {
            const int start = max(end_ph - WIN * (pn - p), 0);
            const int end_  = min(start + WIN, len);
            const int wlen  = end_ - start;
            const int col   = tgt[b * P_ + p];
            // For t < wlen: f = start + t is provably in [0, F_) — no clamp needed.
            const float* Xp = X + ((size_t)b * F_ + (size_t)start) * C_ + col;

            float vals[WIN];
            if (wlen == WIN) {
                #pragma unroll
                for (int t = 0; t < WIN; ++t)
                    vals[t] = Xp[(size_t)t * C_];
            } else {
                #pragma unroll
                for (int t = 0; t < WIN; ++t)
                    vals[t] = (t < wlen) ? Xp[(size_t)t * C_] : 0.0f;
            }

            // Gaussian taps — computed EXACTLY as in the verified kernel
            // (absmax was 0.0; do not perturb numerics).
            float g[9];
            float gs = 0.0f;
            #pragma unroll
            for (int i = 0; i < 9; ++i) {
                const float x = (float)(i - 4) * 0.25f;  // /SIGMA=4
                g[i] = __expf(-0.5f * x * x);
                gs += g[i];
            }
            const float inv = 1.0f / gs;

            float m = -INFINITY;
            if (wlen == WIN) {
                // Fully unrolled: boundary masks resolve at compile time.
                // Skipped taps contributed exactly +0.0 before — bit-identical.
                #pragma unroll
                for (int t = 0; t < WIN; ++t) {
                    float s = 0.0f;
                    #pragma unroll
                    for (int i = 0; i < 9; ++i) {
                        const int j = t + i - 3;
                        if (j >= 0 && j < WIN)
                            s = fmaf(g[i], vals[j], s);
                    }
                    m = fmaxf(m, s * inv);
                }
                contrib = -m;
            } else {
                for (int t = 0; t < wlen; ++t) {
                    float s = 0.0f;
                    #pragma unroll
                    for (int i = 0; i < 9; ++i) {
                        const int j = t + i - 3;
                        const float v = (j >= 0 && j < WIN) ? vals[j] : 0.0f;
                        s = fmaf(g[i], v, s);
                    }
                    m = fmaxf(m, s * inv);
                }
                if (wlen > 0) contrib = -m;
            }
        }
    } else {
        // -------- silence term: SIL_SPLIT blocks per batch --------
        const int sb = blockIdx.x - B_;
        const int b  = sb >> 4;          // / SIL_SPLIT
        const int c  = sb & (SIL_SPLIT - 1);
        const int pn = phoneme_nums[b];
        const int len = lengths[b];
        const int end_ph = min(p_end[b] + OFFSET, len);
        const int first_start = max(end_ph - WIN * pn, 0);
        const int start_last  = max(end_ph - WIN, 0);
        const int last_end    = min(start_last + WIN, len);
        const float* Xb = X + (size_t)b * F_ * C_;  // SIL column = 0

        // F_/ (256*SIL_SPLIT) = 2 frames per thread; both loads independent.
        const int f0 = c * 256 + tid;        // 0..4095
        const int f1 = f0 + 256 * SIL_SPLIT; // 4096..8191
        float s = 0.0f;
        if (f0 < len && ((f0 < first_start) | (f0 >= last_end)))
            s += Xb[(size_t)f0 * C_];
        if (f1 < len && ((f1 < first_start) | (f1 >= last_end)))
            s += Xb[(size_t)f1 * C_];
        contrib = -s;
    }

    // -------- block reduction: wave shuffle then LDS --------
    #pragma unroll
    for (int off = 32; off > 0; off >>= 1)
        contrib += __shfl_down(contrib, off, 64);
    const int lane = tid & 63;
    const int wave = tid >> 6;
    if (lane == 0) sdata[wave] = contrib;
    __syncthreads();
    if (tid == 0) {
        const float tot = sdata[0] + sdata[1] + sdata[2] + sdata[3];
        atomicAdd(out, tot);
    }
}

extern "C" void kernel_launch(void* const* d_in, const int* in_sizes, int n_in,
                              void* d_out, int out_size, void* d_ws, size_t ws_size,
                              hipStream_t stream) {
    const float* X            = (const float*)d_in[0];
    const int* lengths        = (const int*)d_in[1];
    const int* tgt            = (const int*)d_in[2];
    const int* p_end          = (const int*)d_in[3];
    const int* phoneme_nums   = (const int*)d_in[4];
    float* out = (float*)d_out;

    // Zero the accumulator with a memset node instead of a 1-thread kernel
    // (one fewer serialized dispatch in the captured graph).
    hipMemsetAsync(out, 0, sizeof(float), stream);
    smoothed_loss_kernel<<<B_ + B_ * SIL_SPLIT, 256, 0, stream>>>(
        X, lengths, tgt, p_end, phoneme_nums, out);
}